// Round 3
// baseline (70.253 us; speedup 1.0000x reference)
//
#include <hip/hip_runtime.h>
#include <cstdint>
#include <cstddef>

#define N_MASKS 96
#define HW (512 * 512)
#define WORDS_PER_ROW (HW / 64)             // 4096 u64 words per mask row
#define VECS_PER_ROW (WORDS_PER_ROW / 2)    // 2048 ulonglong2 per row
#define TOTAL_WORDS (N_MASKS * WORDS_PER_ROW)
#define P_BOXES 8
#define SCORE_THR 0.5f
#define SCORE_BONUS 0.05f
#define TILE 4
#define NT (N_MASKS / TILE)                 // 24 tiles per dim
#define ACTIVE_TILES (NT * (NT + 1) / 2)    // 300 upper-triangular tiles

// ---------------------------------------------------------------------------
// Kernel 1: binarize mask logits into bit-packed rows (ballot pack).
// Also zeroes the completion counter for kernel 2 (visible at kernel boundary).
// ---------------------------------------------------------------------------
__global__ __launch_bounds__(256) void pack_kernel(
    const float4* __restrict__ logits,
    unsigned long long* __restrict__ bits,
    int* counter) {
  if (blockIdx.x == 0 && threadIdx.x == 0) *counter = 0;
  int wave = (blockIdx.x * blockDim.x + threadIdx.x) >> 6;
  int lane = threadIdx.x & 63;
  size_t g0 = (size_t)wave * 4;
  float4 v0 = logits[(g0 + 0) * 64 + lane];
  float4 v1 = logits[(g0 + 1) * 64 + lane];
  float4 v2 = logits[(g0 + 2) * 64 + lane];
  float4 v3 = logits[(g0 + 3) * 64 + lane];
  unsigned long long m[16];
  m[0]  = __ballot(v0.x > 0.0f); m[1]  = __ballot(v0.y > 0.0f);
  m[2]  = __ballot(v0.z > 0.0f); m[3]  = __ballot(v0.w > 0.0f);
  m[4]  = __ballot(v1.x > 0.0f); m[5]  = __ballot(v1.y > 0.0f);
  m[6]  = __ballot(v1.z > 0.0f); m[7]  = __ballot(v1.w > 0.0f);
  m[8]  = __ballot(v2.x > 0.0f); m[9]  = __ballot(v2.y > 0.0f);
  m[10] = __ballot(v2.z > 0.0f); m[11] = __ballot(v2.w > 0.0f);
  m[12] = __ballot(v3.x > 0.0f); m[13] = __ballot(v3.y > 0.0f);
  m[14] = __ballot(v3.z > 0.0f); m[15] = __ballot(v3.w > 0.0f);
  if (lane == 0) {
    unsigned long long* dst = bits + g0 * 4;
#pragma unroll
    for (int k = 0; k < 16; ++k) dst[k] = m[k];
  }
}

// ---------------------------------------------------------------------------
// Kernel 2: pairwise intersections (4x4 tile per block) + fused finalize in
// the last-finishing block (agent-scope atomics for cross-XCD safety).
// ---------------------------------------------------------------------------
__global__ __launch_bounds__(256) void inter_finalize_kernel(
    const unsigned long long* __restrict__ bits,
    int* inter, int* counter,
    const float* __restrict__ scores,
    const float* __restrict__ pboxes,
    const float* __restrict__ qboxes,
    float* __restrict__ out) {
  __shared__ int red[4][TILE * TILE];
  __shared__ bool s_last;
  __shared__ int s_int[N_MASKS * N_MASKS];
  __shared__ float s_scores[N_MASKS];
  __shared__ int s_order[N_MASKS];
  __shared__ float s_comb[P_BOXES * N_MASKS];
  __shared__ float s_pb[P_BOXES * 4];
  __shared__ float s_qb[N_MASKS * 4];

  int t = threadIdx.x;

  // ---- map linear block id -> upper-triangular tile (ty, tx), tx >= ty ----
  int b = blockIdx.x, ty = 0;
  while (b >= NT - ty) { b -= NT - ty; ++ty; }
  int tx = ty + b;
  int bi = ty * TILE, bj = tx * TILE;

  // ---- 4x4 tile of intersection counts ----
  const ulonglong2* base = (const ulonglong2*)bits;
  int acc[TILE * TILE];
#pragma unroll
  for (int k = 0; k < TILE * TILE; ++k) acc[k] = 0;
#pragma unroll
  for (int w = 0; w < VECS_PER_ROW / 256; ++w) {  // 8 iterations
    int idx = w * 256 + t;
    ulonglong2 a[TILE], bb[TILE];
#pragma unroll
    for (int r = 0; r < TILE; ++r)
      a[r] = base[(size_t)(bi + r) * VECS_PER_ROW + idx];
#pragma unroll
    for (int c = 0; c < TILE; ++c)
      bb[c] = base[(size_t)(bj + c) * VECS_PER_ROW + idx];
#pragma unroll
    for (int r = 0; r < TILE; ++r)
#pragma unroll
      for (int c = 0; c < TILE; ++c)
        acc[r * TILE + c] += __popcll(a[r].x & bb[c].x) + __popcll(a[r].y & bb[c].y);
  }
#pragma unroll
  for (int k = 0; k < TILE * TILE; ++k)
    for (int off = 32; off >= 1; off >>= 1) acc[k] += __shfl_xor(acc[k], off);
  int wv = t >> 6;
  if ((t & 63) == 0) {
#pragma unroll
    for (int k = 0; k < TILE * TILE; ++k) red[wv][k] = acc[k];
  }
  __syncthreads();
  if (t < TILE * TILE) {
    int tot = red[0][t] + red[1][t] + red[2][t] + red[3][t];
    int i = bi + (t >> 2), j = bj + (t & 3);
    if (j >= i) {
      __hip_atomic_store(&inter[i * N_MASKS + j], tot, __ATOMIC_RELAXED, __HIP_MEMORY_SCOPE_AGENT);
      __hip_atomic_store(&inter[j * N_MASKS + i], tot, __ATOMIC_RELAXED, __HIP_MEMORY_SCOPE_AGENT);
    }
  }
  __syncthreads();  // stores (vmcnt-drained) complete before the ticket
  if (t == 0) {
    int ticket = __hip_atomic_fetch_add(counter, 1, __ATOMIC_ACQ_REL, __HIP_MEMORY_SCOPE_AGENT);
    s_last = (ticket == ACTIVE_TILES - 1);
  }
  __syncthreads();
  if (!s_last) return;

  // =================== finalize (runs in exactly one block) ===============
  if (t < N_MASKS) s_scores[t] = scores[t];
  for (int k = t; k < P_BOXES * 4; k += 256) s_pb[k] = pboxes[k];
  for (int k = t; k < N_MASKS * 4; k += 256) s_qb[k] = qboxes[k];
  for (int e = t; e < N_MASKS * N_MASKS; e += 256)
    s_int[e] = __hip_atomic_load(&inter[e], __ATOMIC_RELAXED, __HIP_MEMORY_SCOPE_AGENT);
  __syncthreads();

  // stable descending rank of scores (tie -> smaller index first)
  if (t < N_MASKS) {
    float sc = s_scores[t];
    int r = 0;
    for (int m = 0; m < N_MASKS; ++m) {
      float sm = s_scores[m];
      if (sm > sc || (sm == sc && m < t)) ++r;
    }
    s_order[r] = t;
  }
  // combined = box_iou(prompt, query) + bonus * score (same f32 ops as ref)
  for (int f = t; f < P_BOXES * N_MASKS; f += 256) {
    int p = f / N_MASKS, q = f % N_MASKS;
    float ax0 = s_pb[p * 4 + 0], ay0 = s_pb[p * 4 + 1];
    float ax1 = s_pb[p * 4 + 2], ay1 = s_pb[p * 4 + 3];
    float bx0 = s_qb[q * 4 + 0], by0 = s_qb[q * 4 + 1];
    float bx1 = s_qb[q * 4 + 2], by1 = s_qb[q * 4 + 3];
    float ltx = fmaxf(ax0, bx0), lty = fmaxf(ay0, by0);
    float rbx = fminf(ax1, bx1), rby = fminf(ay1, by1);
    float w = fmaxf(rbx - ltx, 0.0f), h = fmaxf(rby - lty, 0.0f);
    float in_ = w * h;
    float aa = fmaxf(ax1 - ax0, 0.0f) * fmaxf(ay1 - ay0, 0.0f);
    float ab = fmaxf(bx1 - bx0, 0.0f) * fmaxf(by1 - by0, 0.0f);
    float un = aa + ab - in_;
    float iou = (un > 0.0f) ? in_ / un : 0.0f;
    s_comb[f] = iou + SCORE_BONUS * s_scores[q];
  }
  __syncthreads();

  if (t < 64) {
    // ---------------- wave 0: greedy NMS, bit-columns in registers --------
    // IoU > 0.5  <=>  3*inter > area_i + area_j  (exact integer compare;
    // union==0 => inter==0 => false, matching where(union>0, ...) > 0.5)
    int lane = t;
    int oc1 = s_order[lane];
    int oc2 = (lane < 32) ? s_order[lane + 64] : 0;
    int a1 = s_int[oc1 * N_MASKS + oc1];
    int a2 = s_int[oc2 * N_MASKS + oc2];
    unsigned long long c1_lo = 0, c1_hi = 0, c2_lo = 0, c2_hi = 0;
    for (int i = 0; i < N_MASKS; ++i) {
      int oi = s_order[i];
      int ai = s_int[oi * N_MASKS + oi];
      bool t1 = 3 * s_int[oi * N_MASKS + oc1] > ai + a1;
      bool t2 = (lane < 32) && (3 * s_int[oi * N_MASKS + oc2] > ai + a2);
      unsigned long long bit = 1ull << (i & 63);
      if (i < 64) { if (t1) c1_lo |= bit; if (t2) c2_lo |= bit; }
      else        { if (t1) c1_hi |= bit; if (t2) c2_hi |= bit; }
    }
    // eligibility masks over sorted positions
    unsigned long long el_lo = __ballot(s_scores[oc1] >= SCORE_THR);
    unsigned long long el_hi = __ballot((lane < 32) && (s_scores[oc2] >= SCORE_THR));
    if ((el_lo | el_hi) == 0ull) { el_lo = ~0ull; el_hi = ~0ull; }

    bool k1 = false, k2 = false;
    for (int i = 0; i < N_MASKS; ++i) {
      bool c;
      bool el;
      if (i < 64) {
        unsigned long long bit = 1ull << i;
        c = (k1 && (c1_lo & bit)) || (k2 && (c2_lo & bit));
        el = (el_lo >> i) & 1ull;
      } else {
        unsigned long long bit = 1ull << (i - 64);
        c = (k1 && (c1_hi & bit)) || (k2 && (c2_hi & bit));
        el = (el_hi >> (i - 64)) & 1ull;
      }
      bool sup = __any(c);
      bool ki = el && !sup;
      if (lane == i) k1 = ki;
      if (lane + 64 == i) k2 = ki;
    }
    out[oc1] = k1 ? s_scores[oc1] : 0.0f;
    if (lane < 32) out[oc2] = k2 ? s_scores[oc2] : 0.0f;
  } else if (t < 128) {
    // ---------------- wave 1: greedy bipartite matching -------------------
    int lane = t & 63;
    unsigned assigned_p = 0;
    unsigned long long used_lo = 0, used_hi = 0;
    int assign_q[P_BOXES];
#pragma unroll
    for (int p = 0; p < P_BOXES; ++p) assign_q[p] = -1;

    for (int it = 0; it < P_BOXES; ++it) {
      float bv = -1.0f;
      int bf = 1 << 30;
#pragma unroll
      for (int k = 0; k < (P_BOXES * N_MASKS) / 64; ++k) {
        int f = lane + 64 * k;
        int p = f / N_MASKS, q = f % N_MASKS;
        bool pv = !((assigned_p >> p) & 1u);
        bool qv = (q < 64) ? !((used_lo >> q) & 1ull) : !((used_hi >> (q - 64)) & 1ull);
        if (pv && qv) {
          float v = s_comb[f];
          if (v > bv || (v == bv && f < bf)) { bv = v; bf = f; }
        }
      }
      for (int off = 32; off >= 1; off >>= 1) {
        float ov = __shfl_xor(bv, off);
        int of = __shfl_xor(bf, off);
        if (ov > bv || (ov == bv && of < bf)) { bv = ov; bf = of; }
      }
      if (bf < (1 << 30)) {
        int p = bf / N_MASKS, q = bf % N_MASKS;
        assigned_p |= 1u << p;
        if (q < 64) used_lo |= 1ull << q;
        else used_hi |= 1ull << (q - 64);
        assign_q[p] = q;
      }
    }
    // fallback (unreachable for P=8 <= Q=96, kept for fidelity)
#pragma unroll
    for (int p = 0; p < P_BOXES; ++p) {
      if (assign_q[p] < 0) {
        float best = -1e30f;
        int bq = 0;
        for (int q = 0; q < N_MASKS; ++q) {
          bool used = (q < 64) ? ((used_lo >> q) & 1ull) : ((used_hi >> (q - 64)) & 1ull);
          float v = used ? -1e30f : s_scores[q];
          if (v > best) { best = v; bq = q; }
        }
        assign_q[p] = bq;
        if (bq < 64) used_lo |= 1ull << bq;
        else used_hi |= 1ull << (bq - 64);
      }
    }
#pragma unroll
    for (int p = 0; p < P_BOXES; ++p) {
      if (lane == p) out[N_MASKS + p] = s_comb[p * N_MASKS + assign_q[p]];
    }
  }
}

extern "C" void kernel_launch(void* const* d_in, const int* in_sizes, int n_in,
                              void* d_out, int out_size, void* d_ws, size_t ws_size,
                              hipStream_t stream) {
  const float* mask_logits = (const float*)d_in[0];
  const float* scores = (const float*)d_in[1];
  const float* pboxes = (const float*)d_in[2];
  const float* qboxes = (const float*)d_in[3];
  float* out = (float*)d_out;

  // ws layout: [bits: TOTAL_WORDS u64][inter: 96*96 int][counter: 1 int]
  unsigned long long* bits = (unsigned long long*)d_ws;
  int* inter = (int*)((char*)d_ws + (size_t)TOTAL_WORDS * sizeof(unsigned long long));
  int* counter = inter + N_MASKS * N_MASKS;

  int total_waves = (TOTAL_WORDS / 4) / 4;      // 24576
  int pack_blocks = (total_waves * 64) / 256;   // 6144
  pack_kernel<<<pack_blocks, 256, 0, stream>>>((const float4*)mask_logits, bits, counter);

  inter_finalize_kernel<<<ACTIVE_TILES, 256, 0, stream>>>(
      bits, inter, counter, scores, pboxes, qboxes, out);
}

// Round 4
// 62.409 us; speedup vs baseline: 1.1257x; 1.1257x over previous
//
#include <hip/hip_runtime.h>
#include <cstdint>
#include <cstddef>

#define N_MASKS 96
#define HW (512 * 512)
#define WORDS_PER_ROW (HW / 64)             // 4096 u64 words per mask row
#define VECS_PER_ROW (WORDS_PER_ROW / 2)    // 2048 ulonglong2 per row
#define TOTAL_WORDS (N_MASKS * WORDS_PER_ROW)
#define P_BOXES 8
#define SCORE_THR 0.5f
#define SCORE_BONUS 0.05f
#define TILE 4

// ---------------------------------------------------------------------------
// Kernel 1: binarize mask logits into bit-packed rows (ballot pack).
// Each wave: 4 groups of 256 elements, 4 float4 loads/lane in flight.
// ---------------------------------------------------------------------------
__global__ __launch_bounds__(256) void pack_kernel(
    const float4* __restrict__ logits,
    unsigned long long* __restrict__ bits) {
  int wave = (blockIdx.x * blockDim.x + threadIdx.x) >> 6;
  int lane = threadIdx.x & 63;
  size_t g0 = (size_t)wave * 4;
  float4 v0 = logits[(g0 + 0) * 64 + lane];
  float4 v1 = logits[(g0 + 1) * 64 + lane];
  float4 v2 = logits[(g0 + 2) * 64 + lane];
  float4 v3 = logits[(g0 + 3) * 64 + lane];
  unsigned long long m[16];
  m[0]  = __ballot(v0.x > 0.0f); m[1]  = __ballot(v0.y > 0.0f);
  m[2]  = __ballot(v0.z > 0.0f); m[3]  = __ballot(v0.w > 0.0f);
  m[4]  = __ballot(v1.x > 0.0f); m[5]  = __ballot(v1.y > 0.0f);
  m[6]  = __ballot(v1.z > 0.0f); m[7]  = __ballot(v1.w > 0.0f);
  m[8]  = __ballot(v2.x > 0.0f); m[9]  = __ballot(v2.y > 0.0f);
  m[10] = __ballot(v2.z > 0.0f); m[11] = __ballot(v2.w > 0.0f);
  m[12] = __ballot(v3.x > 0.0f); m[13] = __ballot(v3.y > 0.0f);
  m[14] = __ballot(v3.z > 0.0f); m[15] = __ballot(v3.w > 0.0f);
  if (lane == 0) {
    unsigned long long* dst = bits + g0 * 4;
#pragma unroll
    for (int k = 0; k < 16; ++k) dst[k] = m[k];
  }
}

// ---------------------------------------------------------------------------
// Kernel 2: pairwise intersection counts, 4x4 pairs per block (R2-proven).
// ---------------------------------------------------------------------------
__global__ __launch_bounds__(256) void inter_kernel(
    const unsigned long long* __restrict__ bits,
    int* __restrict__ inter) {
  int bi = blockIdx.y * TILE, bj = blockIdx.x * TILE;
  if (bj + TILE - 1 < bi) return;  // tile entirely strictly-lower: skip
  int t = threadIdx.x;
  const ulonglong2* base = (const ulonglong2*)bits;
  int acc[TILE * TILE];
#pragma unroll
  for (int k = 0; k < TILE * TILE; ++k) acc[k] = 0;

#pragma unroll
  for (int w = 0; w < VECS_PER_ROW / 256; ++w) {  // 8 iterations
    int idx = w * 256 + t;
    ulonglong2 a[TILE], b[TILE];
#pragma unroll
    for (int r = 0; r < TILE; ++r)
      a[r] = base[(size_t)(bi + r) * VECS_PER_ROW + idx];
#pragma unroll
    for (int c = 0; c < TILE; ++c)
      b[c] = base[(size_t)(bj + c) * VECS_PER_ROW + idx];
#pragma unroll
    for (int r = 0; r < TILE; ++r)
#pragma unroll
      for (int c = 0; c < TILE; ++c)
        acc[r * TILE + c] += __popcll(a[r].x & b[c].x) + __popcll(a[r].y & b[c].y);
  }
#pragma unroll
  for (int k = 0; k < TILE * TILE; ++k)
    for (int off = 32; off >= 1; off >>= 1) acc[k] += __shfl_xor(acc[k], off);
  __shared__ int red[4][TILE * TILE];
  int wv = t >> 6;
  if ((t & 63) == 0) {
#pragma unroll
    for (int k = 0; k < TILE * TILE; ++k) red[wv][k] = acc[k];
  }
  __syncthreads();
  if (t < TILE * TILE) {
    int tot = red[0][t] + red[1][t] + red[2][t] + red[3][t];
    int i = bi + (t >> 2), j = bj + (t & 3);
    if (j >= i) {
      inter[i * N_MASKS + j] = tot;
      inter[j * N_MASKS + i] = tot;
    }
  }
}

// ---------------------------------------------------------------------------
// Kernel 3: NMS + greedy box matching. Single block, 128 threads (2 waves).
// Wave 0: register-bit-column greedy NMS with the exact integer threshold
//         3*inter > area_i + area_j  (== f32-rounded iou > 0.5, proven R3).
// Wave 1: greedy bipartite matching.
// ---------------------------------------------------------------------------
__global__ __launch_bounds__(128) void finalize_kernel(
    const int* __restrict__ inter,
    const float* __restrict__ scores,
    const float* __restrict__ pboxes,
    const float* __restrict__ qboxes,
    float* __restrict__ out) {
  __shared__ int s_int[N_MASKS * N_MASKS];
  __shared__ float s_scores[N_MASKS];
  __shared__ int s_order[N_MASKS];
  __shared__ float s_comb[P_BOXES * N_MASKS];
  __shared__ float s_pb[P_BOXES * 4];
  __shared__ float s_qb[N_MASKS * 4];
  int t = threadIdx.x;

  if (t < N_MASKS) s_scores[t] = scores[t];
  for (int k = t; k < P_BOXES * 4; k += 128) s_pb[k] = pboxes[k];
  for (int k = t; k < N_MASKS * 4; k += 128) s_qb[k] = qboxes[k];
  for (int e = t; e < N_MASKS * N_MASKS; e += 128) s_int[e] = inter[e];
  __syncthreads();

  // stable descending rank of scores (tie -> smaller index first)
  if (t < N_MASKS) {
    float sc = s_scores[t];
    int r = 0;
    for (int m = 0; m < N_MASKS; ++m) {
      float sm = s_scores[m];
      if (sm > sc || (sm == sc && m < t)) ++r;
    }
    s_order[r] = t;
  }
  // combined = box_iou(prompt, query) + bonus * score (same f32 ops as ref)
  for (int f = t; f < P_BOXES * N_MASKS; f += 128) {
    int p = f / N_MASKS, q = f % N_MASKS;
    float ax0 = s_pb[p * 4 + 0], ay0 = s_pb[p * 4 + 1];
    float ax1 = s_pb[p * 4 + 2], ay1 = s_pb[p * 4 + 3];
    float bx0 = s_qb[q * 4 + 0], by0 = s_qb[q * 4 + 1];
    float bx1 = s_qb[q * 4 + 2], by1 = s_qb[q * 4 + 3];
    float ltx = fmaxf(ax0, bx0), lty = fmaxf(ay0, by0);
    float rbx = fminf(ax1, bx1), rby = fminf(ay1, by1);
    float w = fmaxf(rbx - ltx, 0.0f), h = fmaxf(rby - lty, 0.0f);
    float in_ = w * h;
    float aa = fmaxf(ax1 - ax0, 0.0f) * fmaxf(ay1 - ay0, 0.0f);
    float ab = fmaxf(bx1 - bx0, 0.0f) * fmaxf(by1 - by0, 0.0f);
    float un = aa + ab - in_;
    float iou = (un > 0.0f) ? in_ / un : 0.0f;
    s_comb[f] = iou + SCORE_BONUS * s_scores[q];
  }
  __syncthreads();

  if (t < 64) {
    // ---------------- wave 0: greedy NMS, bit-columns in registers --------
    int lane = t;
    int oc1 = s_order[lane];
    int oc2 = (lane < 32) ? s_order[lane + 64] : 0;
    int a1 = s_int[oc1 * N_MASKS + oc1];
    int a2 = s_int[oc2 * N_MASKS + oc2];
    unsigned long long c1_lo = 0, c1_hi = 0, c2_lo = 0, c2_hi = 0;
    for (int i = 0; i < N_MASKS; ++i) {
      int oi = s_order[i];
      int ai = s_int[oi * N_MASKS + oi];
      bool t1 = 3 * s_int[oi * N_MASKS + oc1] > ai + a1;
      bool t2 = (lane < 32) && (3 * s_int[oi * N_MASKS + oc2] > ai + a2);
      unsigned long long bit = 1ull << (i & 63);
      if (i < 64) { if (t1) c1_lo |= bit; if (t2) c2_lo |= bit; }
      else        { if (t1) c1_hi |= bit; if (t2) c2_hi |= bit; }
    }
    // eligibility masks over sorted positions
    unsigned long long el_lo = __ballot(s_scores[oc1] >= SCORE_THR);
    unsigned long long el_hi = __ballot((lane < 32) && (s_scores[oc2] >= SCORE_THR));
    if ((el_lo | el_hi) == 0ull) { el_lo = ~0ull; el_hi = ~0ull; }

    bool k1 = false, k2 = false;
    for (int i = 0; i < N_MASKS; ++i) {
      bool c, el;
      if (i < 64) {
        unsigned long long bit = 1ull << i;
        c = (k1 && (c1_lo & bit)) || (k2 && (c2_lo & bit));
        el = (el_lo >> i) & 1ull;
      } else {
        unsigned long long bit = 1ull << (i - 64);
        c = (k1 && (c1_hi & bit)) || (k2 && (c2_hi & bit));
        el = (el_hi >> (i - 64)) & 1ull;
      }
      bool sup = __any(c);
      bool ki = el && !sup;
      if (lane == i) k1 = ki;
      if (lane + 64 == i) k2 = ki;
    }
    out[oc1] = k1 ? s_scores[oc1] : 0.0f;
    if (lane < 32) out[oc2] = k2 ? s_scores[oc2] : 0.0f;
  } else {
    // ---------------- wave 1: greedy bipartite matching -------------------
    int lane = t & 63;
    unsigned assigned_p = 0;
    unsigned long long used_lo = 0, used_hi = 0;
    int assign_q[P_BOXES];
#pragma unroll
    for (int p = 0; p < P_BOXES; ++p) assign_q[p] = -1;

    for (int it = 0; it < P_BOXES; ++it) {
      float bv = -1.0f;
      int bf = 1 << 30;
#pragma unroll
      for (int k = 0; k < (P_BOXES * N_MASKS) / 64; ++k) {
        int f = lane + 64 * k;
        int p = f / N_MASKS, q = f % N_MASKS;
        bool pv = !((assigned_p >> p) & 1u);
        bool qv = (q < 64) ? !((used_lo >> q) & 1ull) : !((used_hi >> (q - 64)) & 1ull);
        if (pv && qv) {
          float v = s_comb[f];
          if (v > bv || (v == bv && f < bf)) { bv = v; bf = f; }
        }
      }
      for (int off = 32; off >= 1; off >>= 1) {
        float ov = __shfl_xor(bv, off);
        int of = __shfl_xor(bf, off);
        if (ov > bv || (ov == bv && of < bf)) { bv = ov; bf = of; }
      }
      if (bf < (1 << 30)) {
        int p = bf / N_MASKS, q = bf % N_MASKS;
        assigned_p |= 1u << p;
        if (q < 64) used_lo |= 1ull << q;
        else used_hi |= 1ull << (q - 64);
        assign_q[p] = q;
      }
    }
    // fallback (unreachable for P=8 <= Q=96, kept for fidelity)
#pragma unroll
    for (int p = 0; p < P_BOXES; ++p) {
      if (assign_q[p] < 0) {
        float best = -1e30f;
        int bq = 0;
        for (int q = 0; q < N_MASKS; ++q) {
          bool used = (q < 64) ? ((used_lo >> q) & 1ull) : ((used_hi >> (q - 64)) & 1ull);
          float v = used ? -1e30f : s_scores[q];
          if (v > best) { best = v; bq = q; }
        }
        assign_q[p] = bq;
        if (bq < 64) used_lo |= 1ull << bq;
        else used_hi |= 1ull << (bq - 64);
      }
    }
#pragma unroll
    for (int p = 0; p < P_BOXES; ++p) {
      if (lane == p) out[N_MASKS + p] = s_comb[p * N_MASKS + assign_q[p]];
    }
  }
}

extern "C" void kernel_launch(void* const* d_in, const int* in_sizes, int n_in,
                              void* d_out, int out_size, void* d_ws, size_t ws_size,
                              hipStream_t stream) {
  const float* mask_logits = (const float*)d_in[0];
  const float* scores = (const float*)d_in[1];
  const float* pboxes = (const float*)d_in[2];
  const float* qboxes = (const float*)d_in[3];
  float* out = (float*)d_out;

  // ws layout: [bits: TOTAL_WORDS u64][inter: 96*96 int]
  unsigned long long* bits = (unsigned long long*)d_ws;
  int* inter = (int*)((char*)d_ws + (size_t)TOTAL_WORDS * sizeof(unsigned long long));

  int total_waves = (TOTAL_WORDS / 4) / 4;      // 24576
  int pack_blocks = (total_waves * 64) / 256;   // 6144
  pack_kernel<<<pack_blocks, 256, 0, stream>>>((const float4*)mask_logits, bits);

  dim3 g2(N_MASKS / TILE, N_MASKS / TILE);      // 24 x 24
  inter_kernel<<<g2, 256, 0, stream>>>(bits, inter);

  finalize_kernel<<<1, 128, 0, stream>>>(inter, scores, pboxes, qboxes, out);
}